// Round 13
// baseline (114.013 us; speedup 1.0000x reference)
//
#include <hip/hip_runtime.h>

typedef __attribute__((ext_vector_type(8))) short short8;
typedef __attribute__((ext_vector_type(4))) float f32x4;
typedef unsigned int u32;

#define NB 64
#define NC 3
#define NH 384
#define NW 384
#define HW (NH*NW)
#define NPATCH 576
#define NE 768
#define KDIM 768           // NC*16*16
#define MDIM (NB*NPATCH)   // 36864

#define BM 128
#define NBLK_M (MDIM / BM)     // 288
#define NWG (NBLK_M * 3)       // 864  (BN=256 -> 3 n-blocks)

// two-pass tile images (BK=32 K-steps, fragment order)
#define AKK 24                 // K-steps
#define ATILE 8192             // 128 rows x 32 k x 2B
#define BTILE 16384            // 256 rows x 32 k x 2B
#define WS_A ((size_t)NBLK_M * AKK * ATILE)   // 56,623,104
#define WS_B ((size_t)3 * AKK * BTILE)        // 1,179,648

// prep: write-linear slot mapping, J=8 chains/thread
#define SLOTS (NBLK_M * AKK * 512)     // 3,538,944 16B-slots of wsa
#define PREP_J 8
#define PREP_STRIDE (SLOTS / PREP_J)   // 442,368
#define PREP_BLOCKS (PREP_STRIDE / 256) // 1728

#define GLOBAL_AS __attribute__((address_space(1)))
#define LDS_AS    __attribute__((address_space(3)))

__device__ __forceinline__ unsigned short f2bf(float f) {
    unsigned int u = __builtin_bit_cast(unsigned int, f);
    u += 0x7fffu + ((u >> 16) & 1u);   // round-to-nearest-even
    return (unsigned short)(u >> 16);
}

__device__ __forceinline__ u32 cvtpk(float lo, float hi) {
    u32 r;
    asm("v_cvt_pk_bf16_f32 %0, %1, %2" : "=v"(r) : "v"(lo), "v"(hi));
    return r;
}

__device__ __forceinline__ void gload_lds16(const void* g, void* l) {
    __builtin_amdgcn_global_load_lds((const GLOBAL_AS u32*)g, (LDS_AS u32*)l, 16, 0, 0);
}

// =====================================================================
// PASS 1: gather -> A fragment-order tiles (write-linear, 8 independent
// chains/thread) and proj_w -> B fragment-order tiles.
// =====================================================================
__global__ __launch_bounds__(256) void prep(
    const float* __restrict__ x,
    const int* __restrict__ start_h,
    const int* __restrict__ start_w,
    const float* __restrict__ pw,
    unsigned char* __restrict__ wsa,
    unsigned char* __restrict__ wsb)
{
    const int gid = blockIdx.x;
    if (gid < PREP_BLOCKS) {
        const int t0 = gid * 256 + threadIdx.x;
        float4 f[PREP_J][2];
        #pragma unroll
        for (int j = 0; j < PREP_J; ++j) {
            int sid = t0 + j * PREP_STRIDE;
            int tile = sid >> 9;
            int s    = sid & 511;
            int bm = tile / AKK;
            int kk = tile - bm * AKK;
            int frag = s >> 6, l = s & 63;
            int lk = l >> 4, lr = l & 15;
            int r  = (frag >> 2) * 64 + (frag & 3) * 16 + lr;
            int m  = bm * 128 + r;
            int b  = m / NPATCH;
            int n  = m - b * NPATCH;
            int base = b * (NC * HW) + start_h[b * NPATCH + n] * NW
                     + start_w[b * NPATCH + n];
            int gk = kk * 32 + lk * 8;
            int c  = gk >> 8;
            int h  = (gk >> 4) & 15;
            int w  = gk & 15;
            const float* src = x + base + c * HW + h * NW + w;
            f[j][0] = *reinterpret_cast<const float4*>(src);
            f[j][1] = *reinterpret_cast<const float4*>(src + 4);
        }
        #pragma unroll
        for (int j = 0; j < PREP_J; ++j) {
            int sid = t0 + j * PREP_STRIDE;
            *reinterpret_cast<uint4*>(wsa + (size_t)sid * 16) = make_uint4(
                cvtpk(f[j][0].x, f[j][0].y), cvtpk(f[j][0].z, f[j][0].w),
                cvtpk(f[j][1].x, f[j][1].y), cvtpk(f[j][1].z, f[j][1].w));
        }
    } else {
        int id = (gid - PREP_BLOCKS) * 256 + threadIdx.x;  // 72*1024
        int tile = id >> 10;
        int s    = id & 1023;
        int bn = tile / AKK;
        int kk = tile - bn * AKK;
        int g = s >> 6, l = s & 63;
        int e = bn * 256 + g * 16 + (l & 15);
        int k = kk * 32 + (l >> 4) * 8;
        const float4 f0 = *reinterpret_cast<const float4*>(pw + (size_t)e * KDIM + k);
        const float4 f1 = *reinterpret_cast<const float4*>(pw + (size_t)e * KDIM + k + 4);
        *reinterpret_cast<uint4*>(wsb + (size_t)tile * BTILE + s * 16) =
            make_uint4(cvtpk(f0.x, f0.y), cvtpk(f0.z, f0.w),
                       cvtpk(f1.x, f1.y), cvtpk(f1.z, f1.w));
    }
}

// =====================================================================
// PASS 2: barrier-free register GEMM with ASM-FORCED depth-3 pipeline.
// Volatile global_load_dwordx4 with 64-bit VGPR address + "off" (no saddr
// operand); manual counted vmcnt; 24 loads in flight; load->use distance
// = 2 full MFMA steps. Final WAITV(0) drains asm loads before epilogue so
// the compiler's own vmcnt accounting stays sound.
// =====================================================================
#define WAITV(N) do { asm volatile("s_waitcnt vmcnt(" #N ")" ::: "memory"); \
                      __builtin_amdgcn_sched_barrier(0); } while (0)

__global__ __launch_bounds__(512, 2) void gemm_reg(
    const unsigned char* __restrict__ wsa,
    const unsigned char* __restrict__ wsb,
    const float* __restrict__ pb,
    float* __restrict__ out)
{
    const int tid = threadIdx.x;
    const int bid  = blockIdx.x;
    const int lbid = (bid & 7) * (NWG / 8) + (bid >> 3);   // XCD swizzle
    const int bm = lbid / 3;
    const int bn = lbid - bm * 3;
    const int m0 = bm * BM;
    const int e0 = bn * 256;

    const int lane = tid & 63;
    const int wv   = tid >> 6;       // 0..7
    const int wr   = wv >> 2;        // 0..1 (64 m-rows)
    const int wc   = wv & 3;         // 0..3 (64 e-cols)
    const int lr   = lane & 15;
    const int lk   = lane >> 4;      // 0..3

    // per-lane base pointers (64-bit vaddr form)
    const unsigned char* pA = wsa + (size_t)bm * (AKK * ATILE)
                            + wr * 4096 + lane * 16;
    const unsigned char* pB = wsb + (size_t)bn * (AKK * BTILE)
                            + wc * 4096 + lane * 16;

    f32x4 acc[4][4] = {};
    uint4 a0[4], b0[4], a1[4], b1[4], a2[4], b2[4];

#define ISSUE(KK, AR, BR)                                                     \
    {                                                                         \
        _Pragma("unroll")                                                     \
        for (int mi = 0; mi < 4; ++mi)                                        \
            asm volatile("global_load_dwordx4 %0, %1, off"                    \
                : "=v"(AR[mi])                                                \
                : "v"(pA + ((KK) * ATILE + mi * 1024)));                      \
        _Pragma("unroll")                                                     \
        for (int ni = 0; ni < 4; ++ni)                                        \
            asm volatile("global_load_dwordx4 %0, %1, off"                    \
                : "=v"(BR[ni])                                                \
                : "v"(pB + ((KK) * BTILE + ni * 1024)));                      \
    }

#define STEP(AR, BR)                                                          \
    {                                                                         \
        _Pragma("unroll")                                                     \
        for (int mi = 0; mi < 4; ++mi)                                        \
            _Pragma("unroll")                                                 \
            for (int ni = 0; ni < 4; ++ni)                                    \
                acc[mi][ni] = __builtin_amdgcn_mfma_f32_16x16x32_bf16(        \
                    __builtin_bit_cast(short8, AR[mi]),                       \
                    __builtin_bit_cast(short8, BR[ni]),                       \
                    acc[mi][ni], 0, 0, 0);                                    \
    }

    ISSUE(0, a0, b0)
    ISSUE(1, a1, b1)
    ISSUE(2, a2, b2)

    #pragma unroll
    for (int kk = 0; kk < AKK; kk += 3) {
        // slot 0
        if (kk <= 21) { WAITV(16); } else { WAITV(0); }
        STEP(a0, b0)
        if (kk + 3 < AKK) ISSUE(kk + 3, a0, b0)
        // slot 1
        if (kk + 1 <= 21) { WAITV(16); } else if (kk + 1 == 22) { WAITV(8); } else { WAITV(0); }
        STEP(a1, b1)
        if (kk + 4 < AKK) ISSUE(kk + 4, a1, b1)
        // slot 2
        if (kk + 2 <= 21) { WAITV(16); } else if (kk + 2 == 22) { WAITV(8); } else { WAITV(0); }
        STEP(a2, b2)
        if (kk + 5 < AKK) ISSUE(kk + 5, a2, b2)
    }

#undef ISSUE
#undef STEP

    // ---- epilogue: bias + store (all asm loads already drained) ----
    float biasv[4];
    #pragma unroll
    for (int ni = 0; ni < 4; ++ni)
        biasv[ni] = pb[e0 + wc * 64 + ni * 16 + lr];

    #pragma unroll
    for (int mi = 0; mi < 4; ++mi) {
        #pragma unroll
        for (int j = 0; j < 4; ++j) {
            int row = m0 + wr * 64 + mi * 16 + lk * 4 + j;
            float* orow = out + (size_t)row * NE + e0 + wc * 64 + lr;
            #pragma unroll
            for (int ni = 0; ni < 4; ++ni)
                orow[ni * 16] = acc[mi][ni][j] + biasv[ni];
        }
    }
}

// =====================================================================
// FALLBACK (ws too small for two-pass): R6 fused kernel (78 us proven).
// =====================================================================
__global__ __launch_bounds__(256) void convert_w_row(
    const float* __restrict__ pw, unsigned char* __restrict__ wsb)
{
    int id = blockIdx.x * 256 + threadIdx.x;   // 768*96 = 73728
    int e  = id / 96;
    int ck = id - e * 96;
    int k0 = ck * 8;

    const float4 f0 = *reinterpret_cast<const float4*>(pw + (size_t)e * KDIM + k0);
    const float4 f1 = *reinterpret_cast<const float4*>(pw + (size_t)e * KDIM + k0 + 4);
    int bn = e >> 8;
    int r  = e & 255;
    int kk = k0 >> 6;
    int ch = (k0 & 63) >> 3;
    size_t off = (size_t)(bn * 12 + kk) * 32768 + r * 128
               + ((ch ^ (r & 7)) * 16);
    *reinterpret_cast<uint4*>(wsb + off) = make_uint4(
        cvtpk(f0.x, f0.y), cvtpk(f0.z, f0.w),
        cvtpk(f1.x, f1.y), cvtpk(f1.z, f1.w));
}

template <bool WSB>
__global__ __launch_bounds__(512, 4) void fused_gemm(
    const float* __restrict__ x,
    const int* __restrict__ start_h,
    const int* __restrict__ start_w,
    const float* __restrict__ pw,
    const float* __restrict__ pb,
    const unsigned char* __restrict__ wsb,
    float* __restrict__ out)
{
    __shared__ __align__(16) unsigned short lA[2][BM * 64];
    __shared__ __align__(16) unsigned short lB[256 * 64];
    __shared__ int baseOff[BM];

    const int tid = threadIdx.x;
    const int bid  = blockIdx.x;
    const int lbid = (bid & 7) * (NWG / 8) + (bid >> 3);
    const int bm = lbid / 3;
    const int bn = lbid - bm * 3;
    const int m0 = bm * BM;
    const int e0 = bn * 256;

    if (tid < BM) {
        int m = m0 + tid;
        int b = m / NPATCH;
        int n = m - b * NPATCH;
        baseOff[tid] = b * (NC * HW) + start_h[b * NPATCH + n] * NW
                     + start_w[b * NPATCH + n];
    }

    const int lane = tid & 63;
    const int wv   = tid >> 6;
    const int wr   = wv >> 2;
    const int wc   = wv & 3;
    const int lr   = lane & 15;
    const int lk   = lane >> 4;

    const int rt = tid >> 4;
    const int j0 = (tid & 15) * 4;
    const int chunk  = j0 >> 3;
    const int within = j0 & 7;
    const int hsub   = j0 >> 4;
    const int wsub   = j0 & 15;

    __syncthreads();

    int ab[4];
    #pragma unroll
    for (int i = 0; i < 4; ++i)
        ab[i] = baseOff[i * 32 + rt] + hsub * NW + wsub;

    f32x4 acc[4][4] = {};
    float4 ar[4];

#define LOADA(KK)                                                             \
    {                                                                         \
        const int koff = ((KK) >> 2) * HW + ((KK) & 3) * 4 * NW;              \
        _Pragma("unroll")                                                     \
        for (int i = 0; i < 4; ++i)                                           \
            ar[i] = *reinterpret_cast<const float4*>(x + ab[i] + koff);       \
    }

#define WRITEA(BUF)                                                           \
    {                                                                         \
        _Pragma("unroll")                                                     \
        for (int i = 0; i < 4; ++i) {                                         \
            int r = i * 32 + rt;                                              \
            int off = r * 64 + ((chunk ^ (r & 7)) * 8) + within;              \
            *reinterpret_cast<uint2*>(&lA[BUF][off]) =                        \
                make_uint2(cvtpk(ar[i].x, ar[i].y), cvtpk(ar[i].z, ar[i].w)); \
        }                                                                     \
    }

#define STAGEB(KK)                                                            \
    if (WSB) {                                                                \
        const unsigned char* src = wsb + (size_t)(bn * 12 + (KK)) * 32768     \
                                 + wv * 1024 + lane * 16;                     \
        unsigned char* dst = reinterpret_cast<unsigned char*>(lB) + wv * 1024;\
        _Pragma("unroll")                                                     \
        for (int i = 0; i < 4; ++i)                                           \
            gload_lds16(src + i * 8192, dst + i * 8192);                      \
    } else {                                                                  \
        _Pragma("unroll")                                                     \
        for (int i = 0; i < 8; ++i) {                                         \
            int r = i * 32 + rt;                                              \
            const float4 wf = *reinterpret_cast<const float4*>(               \
                pw + (size_t)(e0 + r) * KDIM + (KK) * 64 + j0);               \
            int off = r * 64 + ((chunk ^ (r & 7)) * 8) + within;              \
            *reinterpret_cast<uint2*>(&lB[off]) =                            \
                make_uint2(cvtpk(wf.x, wf.y), cvtpk(wf.z, wf.w));             \
        }                                                                     \
    }

#define COMPUTE(BUF)                                                          \
    {                                                                         \
        _Pragma("unroll")                                                     \
        for (int ks = 0; ks < 2; ++ks) {                                      \
            short8 af[4], bfr[4];                                             \
            _Pragma("unroll")                                                 \
            for (int mi = 0; mi < 4; ++mi) {                                  \
                int row = wr * 64 + mi * 16 + lr;                             \
                int off = row * 64 + (((ks * 4 + lk) ^ (row & 7)) * 8);       \
                af[mi] = *reinterpret_cast<const short8*>(&lA[BUF][off]);     \
            }                                                                 \
            _Pragma("unroll")                                                 \
            for (int ni = 0; ni < 4; ++ni) {                                  \
                int row = wc * 64 + ni * 16 + lr;                             \
                int off = row * 64 + (((ks * 4 + lk) ^ (row & 7)) * 8);       \
                bfr[ni] = *reinterpret_cast<const short8*>(&lB[off]);         \
            }                                                                 \
            _Pragma("unroll")                                                 \
            for (int mi = 0; mi < 4; ++mi)                                    \
                _Pragma("unroll")                                             \
                for (int ni = 0; ni < 4; ++ni)                                \
                    acc[mi][ni] = __builtin_amdgcn_mfma_f32_16x16x32_bf16(    \
                        af[mi], bfr[ni], acc[mi][ni], 0, 0, 0);               \
        }                                                                     \
    }

    LOADA(0)
    WRITEA(0)
    STAGEB(0)
    __syncthreads();

    for (int kk = 0; kk < 12; ++kk) {
        const int buf = kk & 1;
        if (kk + 1 < 12) LOADA(kk + 1)
        COMPUTE(buf)
        __syncthreads();
        if (kk + 1 < 12) {
            WRITEA(buf ^ 1)
            STAGEB(kk + 1)
        }
        __syncthreads();
    }

#undef LOADA
#undef WRITEA
#undef STAGEB
#undef COMPUTE

    float biasv[4];
    #pragma unroll
    for (int ni = 0; ni < 4; ++ni)
        biasv[ni] = pb[e0 + wc * 64 + ni * 16 + lr];

    #pragma unroll
    for (int mi = 0; mi < 4; ++mi) {
        #pragma unroll
        for (int j = 0; j < 4; ++j) {
            int row = m0 + wr * 64 + mi * 16 + lk * 4 + j;
            float* orow = out + (size_t)row * NE + e0 + wc * 64 + lr;
            #pragma unroll
            for (int ni = 0; ni < 4; ++ni)
                orow[ni * 16] = acc[mi][ni][j] + biasv[ni];
        }
    }
}

extern "C" void kernel_launch(void* const* d_in, const int* in_sizes, int n_in,
                              void* d_out, int out_size, void* d_ws, size_t ws_size,
                              hipStream_t stream) {
    const float* x  = (const float*)d_in[0];
    const int* sh   = (const int*)d_in[1];
    const int* sw   = (const int*)d_in[2];
    const float* pw = (const float*)d_in[3];
    const float* pb = (const float*)d_in[4];
    float* out = (float*)d_out;

    if (ws_size >= WS_A + WS_B) {
        unsigned char* wsa = (unsigned char*)d_ws;
        unsigned char* wsb = wsa + WS_A;
        hipLaunchKernelGGL(prep, dim3(PREP_BLOCKS + 288), dim3(256), 0, stream,
                           x, sh, sw, pw, wsa, wsb);
        hipLaunchKernelGGL(gemm_reg, dim3(NWG), dim3(512), 0, stream,
                           wsa, wsb, pb, out);
    } else if (ws_size >= (size_t)1179648) {
        unsigned char* wsb = (unsigned char*)d_ws;
        hipLaunchKernelGGL(convert_w_row, dim3(288), dim3(256), 0, stream, pw, wsb);
        hipLaunchKernelGGL(fused_gemm<true>, dim3(NWG), dim3(512), 0, stream,
                           x, sh, sw, pw, pb, wsb, out);
    } else {
        hipLaunchKernelGGL(fused_gemm<false>, dim3(NWG), dim3(512), 0, stream,
                           x, sh, sw, pw, pb, (const unsigned char*)nullptr, out);
    }
}